// Round 7
// baseline (727.768 us; speedup 1.0000x reference)
//
#include <hip/hip_runtime.h>
#include <math.h>

#define NN 50000
#define NE 800000
#define TT 6
#define HID 48
#define NB 196   // (NN+255)/256
#define LR 65    // LDS row stride for 64 nodes (mod 32 == 1 -> conflict-free)

typedef unsigned short ushortT;

__device__ __forceinline__ float sigmoidf_(float x){ return 1.0f/(1.0f+__expf(-x)); }
__device__ __forceinline__ float tanhf_(float x){
  float xc = fminf(fmaxf(x,-15.f),15.f);
  float t = __expf(2.f*xc);
  return (t-1.f)/(t+1.f);
}
__device__ __forceinline__ unsigned f2bf(float x){
  unsigned u = __float_as_uint(x);
  return (u + 0x7fffu + ((u>>16)&1u)) >> 16;   // RNE to bf16
}
__device__ __forceinline__ unsigned pack2(float a, float b){
  return f2bf(a) | (f2bf(b)<<16);
}
__device__ __forceinline__ float bflo(unsigned u){ return __uint_as_float(u<<16); }
__device__ __forceinline__ float bfhi(unsigned u){ return __uint_as_float(u & 0xffff0000u); }
__device__ __forceinline__ float bfu(ushortT u){ return __uint_as_float(((unsigned)u)<<16); }

struct U3 { unsigned x,y,z; };

// 256-thread inclusive block scan (4 waves of 64)
__device__ __forceinline__ int block_scan_incl(int x, int* wsum){
  int lane = threadIdx.x & 63, w = threadIdx.x >> 6;
  int v = x;
#pragma unroll
  for(int d=1; d<64; d<<=1){
    int u = __shfl_up(v, d, 64);
    if(lane >= d) v += u;
  }
  if(lane==63) wsum[w] = v;
  __syncthreads();
  int add = 0;
#pragma unroll
  for(int k=0;k<3;k++) if(w>k) add += wsum[k];
  return v + add;
}

// ---------------- setup: cnt init + weight repacks ----------------
// Wp  [g 0..2][k 0..47][f' 0..47] = Wih[(g*48+f')*48+k]      (for k_mmG)
// Wgh [wv 0..5][k 0..47][m 0..23] m=(g,j): Whh[(g*48+wv*8+j)*48+k]  (for k_gruF)
__global__ __launch_bounds__(256) void k_setup(int* cnt,
                                               const float* __restrict__ Wih, const float* __restrict__ Whh,
                                               float* Wp, float* Wgh){
  int i = blockIdx.x*256+threadIdx.x;
  if(i<NN) cnt[i]=0;
  if(i < 6912){
    int g = i/2304, rem = i%2304;
    int k = rem/48, f = rem%48;
    Wp[i] = Wih[(g*48+f)*48 + k];
  } else if(i < 13824){
    int idx = i-6912;
    int wv = idx/1152, rem = idx%1152;
    int k = rem/24, m = rem%24;
    int g = m>>3, j = m&7;
    Wgh[idx] = Whh[(g*48+wv*8+j)*48 + k];
  }
}

// single atomic per edge: rank within destination bucket
__global__ __launch_bounds__(256) void k_cnt(const int* __restrict__ ei, int* cnt, int* pos){
  int e = blockIdx.x*256+threadIdx.x;
  if(e<NE){
    int c = ei[NE+e];
    pos[e] = atomicAdd(&cnt[c], 1);
  }
}

__global__ __launch_bounds__(256) void k_partA(const int* __restrict__ cnt, int* bsum){
  __shared__ int wsum[4];
  int i = blockIdx.x*256+threadIdx.x;
  int x = (i<NN)? cnt[i] : 0;
  int lane = threadIdx.x & 63, w = threadIdx.x >> 6;
  int v = x;
#pragma unroll
  for(int m=32;m>=1;m>>=1) v += __shfl_xor(v, m, 64);
  if(lane==0) wsum[w]=v;
  __syncthreads();
  if(threadIdx.x==0) bsum[blockIdx.x] = wsum[0]+wsum[1]+wsum[2]+wsum[3];
}

__global__ __launch_bounds__(256) void k_midB(const int* __restrict__ bsum, int* bpre, int* offs){
  __shared__ int wsum[4];
  int t = threadIdx.x;
  int x = (t<NB)? bsum[t] : 0;
  int incl = block_scan_incl(x, wsum);
  if(t<NB) bpre[t] = incl - x;
  if(t==255) offs[NN] = incl;   // total
}

__global__ __launch_bounds__(256) void k_offsC(const int* __restrict__ cnt, const int* __restrict__ bpre,
                                               int* offs){
  __shared__ int wsum[4];
  int i = blockIdx.x*256+threadIdx.x;
  int x = (i<NN)? cnt[i] : 0;
  int incl = block_scan_incl(x, wsum);
  if(i<NN) offs[i] = bpre[blockIdx.x] + incl - x;
}

// atomic-free scatter: csr[offs[c]+pos[e]] = (row, ew)
__global__ __launch_bounds__(256) void k_scatter(const int* __restrict__ ei, const float* __restrict__ ew,
                                                 const int* __restrict__ offs, const int* __restrict__ pos,
                                                 int2* __restrict__ csr){
  int e = blockIdx.x*256+threadIdx.x;
  if(e<NE){
    int c = ei[NE+e];
    int2 v; v.x = ei[e]; v.y = __float_as_int(ew[e]);
    csr[offs[c]+pos[e]] = v;
  }
}

// deg = 1 + row-sum of ew (atomic-free), dis = rsqrt(deg)
__global__ __launch_bounds__(256) void k_deg(const int2* __restrict__ csr, const int* __restrict__ offs,
                                             float* dis){
  int i = blockIdx.x*256+threadIdx.x;
  if(i<NN){
    float s = 1.f;
    int e0=offs[i], e1=offs[i+1];
    for(int j=e0;j<e1;j++) s += __int_as_float(csr[j].y);
    dis[i] = rsqrtf(s);
  }
}

// patch edge norm in place: y = dis[r]*ew
__global__ __launch_bounds__(256) void k_normE(int2* __restrict__ csr, const float* __restrict__ dis){
  int j = blockIdx.x*256+threadIdx.x;
  if(j<NE){
    int2 v = csr[j];
    v.y = __float_as_int(dis[v.x]*__int_as_float(v.y));
    csr[j] = v;
  }
}

// ---------------- layer-0 matmul: wave = feature slice (uniform), lane = node ----------------
__global__ __launch_bounds__(256) void k_mm0(const float* __restrict__ X, const float* __restrict__ W,
                                             unsigned* __restrict__ A){
  int s = __builtin_amdgcn_readfirstlane(threadIdx.x>>6);   // 0..3, wave-uniform
  int n = blockIdx.x*64 + (threadIdx.x&63);
  if(n>=NN) return;
  const float* xb = X + (long long)n*64;
  const float* wb = W + 12*s;
  float acc[TT][12];
#pragma unroll
  for(int t=0;t<TT;t++)
#pragma unroll
    for(int j=0;j<12;j++) acc[t][j]=0.f;
#pragma unroll 2
  for(int k4=0;k4<16;k4++){
    float4 xv[TT];
#pragma unroll
    for(int t=0;t<TT;t++) xv[t] = *reinterpret_cast<const float4*>(xb + (long long)t*NN*64 + 4*k4);
#pragma unroll
    for(int q=0;q<4;q++){
      const float* wr = wb + (4*k4+q)*HID;
      float w[12];
#pragma unroll
      for(int j=0;j<12;j++) w[j]=wr[j];   // uniform addr -> s_load
#pragma unroll
      for(int t=0;t<TT;t++){
        float xs = (&xv[t].x)[q];
#pragma unroll
        for(int j=0;j<12;j++) acc[t][j] = fmaf(xs, w[j], acc[t][j]);
      }
    }
  }
  unsigned buf[36];
#pragma unroll
  for(int j=0;j<12;j++){
    buf[3*j  ]=pack2(acc[0][j],acc[1][j]);
    buf[3*j+1]=pack2(acc[2][j],acc[3][j]);
    buf[3*j+2]=pack2(acc[4][j],acc[5][j]);
  }
  uint4* o4 = reinterpret_cast<uint4*>(A + (long long)n*144 + 36*s);
#pragma unroll
  for(int q=0;q<9;q++) o4[q] = make_uint4(buf[4*q],buf[4*q+1],buf[4*q+2],buf[4*q+3]);
}

// ---------------- layer-1 matmul (K=48), input fp32 [n][t][48] ----------------
__global__ __launch_bounds__(256) void k_mm1(const float* __restrict__ X, const float* __restrict__ W,
                                             unsigned* __restrict__ A){
  int s = __builtin_amdgcn_readfirstlane(threadIdx.x>>6);
  int n = blockIdx.x*64 + (threadIdx.x&63);
  if(n>=NN) return;
  const float* xb = X + (long long)n*(TT*HID);
  const float* wb = W + 12*s;
  float acc[TT][12];
#pragma unroll
  for(int t=0;t<TT;t++)
#pragma unroll
    for(int j=0;j<12;j++) acc[t][j]=0.f;
#pragma unroll 2
  for(int k4=0;k4<12;k4++){
    float4 xv[TT];
#pragma unroll
    for(int t=0;t<TT;t++) xv[t] = *reinterpret_cast<const float4*>(xb + t*HID + 4*k4);
#pragma unroll
    for(int q=0;q<4;q++){
      const float* wr = wb + (4*k4+q)*HID;
      float w[12];
#pragma unroll
      for(int j=0;j<12;j++) w[j]=wr[j];
#pragma unroll
      for(int t=0;t<TT;t++){
        float xs = (&xv[t].x)[q];
#pragma unroll
        for(int j=0;j<12;j++) acc[t][j] = fmaf(xs, w[j], acc[t][j]);
      }
    }
  }
  unsigned buf[36];
#pragma unroll
  for(int j=0;j<12;j++){
    buf[3*j  ]=pack2(acc[0][j],acc[1][j]);
    buf[3*j+1]=pack2(acc[2][j],acc[3][j]);
    buf[3*j+2]=pack2(acc[4][j],acc[5][j]);
  }
  uint4* o4 = reinterpret_cast<uint4*>(A + (long long)n*144 + 36*s);
#pragma unroll
  for(int q=0;q<9;q++) o4[q] = make_uint4(buf[4*q],buf[4*q+1],buf[4*q+2],buf[4*q+3]);
}

// ---------------- CSR aggregation (bf16 gather) + bias + LN + ReLU (+resid)
__global__ __launch_bounds__(256) void k_agg(const unsigned* __restrict__ A, const float* __restrict__ bias,
                                             const float* __restrict__ gain, const float* __restrict__ beta,
                                             const float* __restrict__ resid, float* __restrict__ out,
                                             const int* __restrict__ offs, const int2* __restrict__ csr,
                                             const float* __restrict__ dis){
  int wid = (blockIdx.x*256+threadIdx.x)>>6;
  int lane = threadIdx.x & 63;
  if(wid>=NN) return;
  const bool act = lane<HID;
  const int f = act? lane : (HID-1);
  float dn = dis[wid];
  float acc[TT];
  {
    U3 v = *reinterpret_cast<const U3*>(A + (long long)wid*144 + 3*f);
    acc[0]=dn*bflo(v.x); acc[1]=dn*bfhi(v.x);
    acc[2]=dn*bflo(v.y); acc[3]=dn*bfhi(v.y);
    acc[4]=dn*bflo(v.z); acc[5]=dn*bfhi(v.z);
  }
  int e0=offs[wid], e1=offs[wid+1];
  int e=e0;
  for(; e+3<e1; e+=4){
    int2 i0=csr[e], i1=csr[e+1], i2=csr[e+2], i3=csr[e+3];
    U3 d0 = *reinterpret_cast<const U3*>(A + (long long)i0.x*144 + 3*f);
    U3 d1 = *reinterpret_cast<const U3*>(A + (long long)i1.x*144 + 3*f);
    U3 d2 = *reinterpret_cast<const U3*>(A + (long long)i2.x*144 + 3*f);
    U3 d3 = *reinterpret_cast<const U3*>(A + (long long)i3.x*144 + 3*f);
    float n0=__int_as_float(i0.y), n1=__int_as_float(i1.y);
    float n2=__int_as_float(i2.y), n3=__int_as_float(i3.y);
    acc[0]=fmaf(n0,bflo(d0.x),acc[0]); acc[1]=fmaf(n0,bfhi(d0.x),acc[1]);
    acc[2]=fmaf(n0,bflo(d0.y),acc[2]); acc[3]=fmaf(n0,bfhi(d0.y),acc[3]);
    acc[4]=fmaf(n0,bflo(d0.z),acc[4]); acc[5]=fmaf(n0,bfhi(d0.z),acc[5]);
    acc[0]=fmaf(n1,bflo(d1.x),acc[0]); acc[1]=fmaf(n1,bfhi(d1.x),acc[1]);
    acc[2]=fmaf(n1,bflo(d1.y),acc[2]); acc[3]=fmaf(n1,bfhi(d1.y),acc[3]);
    acc[4]=fmaf(n1,bflo(d1.z),acc[4]); acc[5]=fmaf(n1,bfhi(d1.z),acc[5]);
    acc[0]=fmaf(n2,bflo(d2.x),acc[0]); acc[1]=fmaf(n2,bfhi(d2.x),acc[1]);
    acc[2]=fmaf(n2,bflo(d2.y),acc[2]); acc[3]=fmaf(n2,bfhi(d2.y),acc[3]);
    acc[4]=fmaf(n2,bflo(d2.z),acc[4]); acc[5]=fmaf(n2,bfhi(d2.z),acc[5]);
    acc[0]=fmaf(n3,bflo(d3.x),acc[0]); acc[1]=fmaf(n3,bfhi(d3.x),acc[1]);
    acc[2]=fmaf(n3,bflo(d3.y),acc[2]); acc[3]=fmaf(n3,bfhi(d3.y),acc[3]);
    acc[4]=fmaf(n3,bflo(d3.z),acc[4]); acc[5]=fmaf(n3,bfhi(d3.z),acc[5]);
  }
  for(; e<e1; ++e){
    int2 i0=csr[e];
    U3 d0 = *reinterpret_cast<const U3*>(A + (long long)i0.x*144 + 3*f);
    float n0=__int_as_float(i0.y);
    acc[0]=fmaf(n0,bflo(d0.x),acc[0]); acc[1]=fmaf(n0,bfhi(d0.x),acc[1]);
    acc[2]=fmaf(n0,bflo(d0.y),acc[2]); acc[3]=fmaf(n0,bfhi(d0.y),acc[3]);
    acc[4]=fmaf(n0,bflo(d0.z),acc[4]); acc[5]=fmaf(n0,bfhi(d0.z),acc[5]);
  }
  float bb = bias[f], gg = gain[f], be = beta[f];
  const float rn = 1.0f/HID;
#pragma unroll
  for(int t=0;t<TT;t++){
    float val = fmaf(acc[t], dn, bb);
    float v = act? val : 0.f;
    float s = v, s2 = v*v;
#pragma unroll
    for(int m=32;m>=1;m>>=1){
      s  += __shfl_xor(s,  m, 64);
      s2 += __shfl_xor(s2, m, 64);
    }
    float mu  = s*rn;
    float var = fmaxf(s2*rn - mu*mu, 0.f);
    float y = (val-mu)*rsqrtf(var+1e-5f)*gg + be;
    y = fmaxf(y, 0.f);
    long long oidx = (long long)wid*(TT*HID) + t*HID + f;
    if(resid) y += resid[oidx];
    if(act) out[oidx] = y;
  }
}

// ---------------- gi = h2 @ Wih^T + bih, bf16 planes [t][f144][n] ----------------
// grid dim3(3,6,196): x=gate, y=t, z=node-block (z slowest -> (t,g) locality on h2)
__global__ __launch_bounds__(256) void k_mmG(const float* __restrict__ h2, const float* __restrict__ Wp,
                                             const float* __restrict__ bih, ushortT* __restrict__ gi){
  int g = blockIdx.x, t = blockIdx.y;
  int n = blockIdx.z*256 + threadIdx.x;
  if(n>=NN) return;
  const float* xr = h2 + (size_t)n*(TT*HID) + t*HID;
  const float* wb = Wp + g*2304;
  const float* bb = bih + g*48;
  float acc[48];
#pragma unroll
  for(int j=0;j<48;j++) acc[j]=bb[j];      // uniform -> s_load
#pragma unroll 2
  for(int k4=0;k4<12;k4++){
    float4 xv = *reinterpret_cast<const float4*>(xr + 4*k4);
#pragma unroll
    for(int q=0;q<4;q++){
      const float* wr = wb + (4*k4+q)*48;
      float w[48];
#pragma unroll
      for(int j=0;j<48;j++) w[j]=wr[j];    // uniform -> s_load
      float xs = (&xv.x)[q];
#pragma unroll
      for(int j=0;j<48;j++) acc[j] = fmaf(xs, w[j], acc[j]);
    }
  }
  size_t base = ((size_t)t*144 + g*48)*NN + n;
#pragma unroll
  for(int j=0;j<48;j++) gi[base + (size_t)j*NN] = (ushortT)f2bf(acc[j]);
}

// ---------------- fused GRU (6 steps, recurrent half only) + classifier ----------------
// block: 64 nodes, 384 threads = 6 waves. Wave wv owns 8 features (f0=wv*8), lane = node.
// h transposed in LDS [48][65]; gi read per-lane coalesced from [t][f][n] planes.
__global__ __launch_bounds__(384) void k_gruF(const ushortT* __restrict__ gi,
                                              const float* __restrict__ Wgh,
                                              const float* __restrict__ bhh,
                                              const float* __restrict__ Wc1, const float* __restrict__ bc1,
                                              const float* __restrict__ Wc2, const float* __restrict__ bc2,
                                              float* __restrict__ out){
  __shared__ float hbuf[48*LR];
  int tid = threadIdx.x;
  int wv = __builtin_amdgcn_readfirstlane(tid>>6);   // 0..5, uniform
  int lane = tid & 63;
  int f0 = wv*8;
  long long nbase = (long long)blockIdx.x*64;

  for(int i=tid;i<48*LR;i+=384) hbuf[i]=0.f;

  float bhr[8], bhz[8], bhn[8];
#pragma unroll
  for(int j=0;j<8;j++){
    int f=f0+j;
    bhr[j] = bhh[f];
    bhz[j] = bhh[48+f];
    bhn[j] = bhh[96+f];
  }

  for(int t=0;t<TT;t++){
    // gate pre-activations for this wave's features (coalesced 128B loads)
    float gr[8], gz[8], gn_[8];
    {
      const ushortT* gp = gi + ((size_t)t*144 + f0)*NN + nbase + lane;
#pragma unroll
      for(int j=0;j<8;j++){
        gr[j]  = bfu(gp[(size_t)j*NN]);
        gz[j]  = bfu(gp[(size_t)(48+j)*NN]);
        gn_[j] = bfu(gp[(size_t)(96+j)*NN]);
      }
    }
    __syncthreads();   // hbuf (prev step) ready

    float ar[8],az[8],an[8];
#pragma unroll
    for(int j=0;j<8;j++){ ar[j]=az[j]=an[j]=0.f; }

#pragma unroll 4
    for(int k=0;k<48;k++){
      const float* wp = Wgh + (wv*48 + k)*24;   // uniform -> s_load
      float ws[24];
#pragma unroll
      for(int q=0;q<24;q++) ws[q]=wp[q];
      float hk = hbuf[k*LR+lane];
#pragma unroll
      for(int j=0;j<8;j++){
        ar[j]=fmaf(hk,ws[j],   ar[j]);
        az[j]=fmaf(hk,ws[8+j], az[j]);
        an[j]=fmaf(hk,ws[16+j],an[j]);
      }
    }

    float hn[8];
#pragma unroll
    for(int j=0;j<8;j++){
      float r  = sigmoidf_(gr[j] + ar[j] + bhr[j]);
      float zg = sigmoidf_(gz[j] + az[j] + bhz[j]);
      float ng = tanhf_(gn_[j] + r*(an[j] + bhn[j]));
      hn[j] = (1.f-zg)*ng + zg*hbuf[(f0+j)*LR+lane];
    }
    __syncthreads();   // all reads done before overwrite
#pragma unroll
    for(int j=0;j<8;j++) hbuf[(f0+j)*LR+lane] = hn[j];
  }
  __syncthreads();     // final h ready

  // classifier epilogue: wave 0 covers the block's 64 nodes
  if(wv==0){
    long long gn = nbase + lane;
    if(gn<NN){
      float hv[24];
#pragma unroll
      for(int j=0;j<24;j++) hv[j]=bc1[j];
      for(int k=0;k<HID;k++){
        float xk = hbuf[k*LR+lane];
        const float* wr = Wc1 + k*24;   // uniform -> s_load
#pragma unroll
        for(int j=0;j<24;j++) hv[j] = fmaf(xk, wr[j], hv[j]);
      }
      float l0=bc2[0], l1=bc2[1];
#pragma unroll
      for(int j=0;j<24;j++){
        float a = fmaxf(hv[j],0.f);
        l0 = fmaf(a, Wc2[2*j],   l0);
        l1 = fmaf(a, Wc2[2*j+1], l1);
      }
      reinterpret_cast<float2*>(out)[gn] = make_float2(l0,l1);
    }
  }
}

static inline size_t al256(size_t x){ return (x+255)&~(size_t)255; }

extern "C" void kernel_launch(void* const* d_in, const int* in_sizes, int n_in,
                              void* d_out, int out_size, void* d_ws, size_t ws_size,
                              hipStream_t stream){
  const float* x_seq=(const float*)d_in[0];
  const int*   ei   =(const int*)d_in[1];
  const float* ew   =(const float*)d_in[2];
  const float* W0=(const float*)d_in[3];  const float* b0=(const float*)d_in[4];
  const float* g0=(const float*)d_in[5];  const float* be0=(const float*)d_in[6];
  const float* W1=(const float*)d_in[7];  const float* b1=(const float*)d_in[8];
  const float* g1=(const float*)d_in[9];  const float* be1=(const float*)d_in[10];
  const float* Wih=(const float*)d_in[11];const float* Whh=(const float*)d_in[12];
  const float* bih=(const float*)d_in[13];const float* bhh=(const float*)d_in[14];
  const float* Wc1=(const float*)d_in[15];const float* bc1=(const float*)d_in[16];
  const float* Wc2=(const float*)d_in[17];const float* bc2=(const float*)d_in[18];
  float* outp=(float*)d_out;

  char* p=(char*)d_ws; size_t off=0;
  auto alloc=[&](size_t bytes)->void*{ void* r=p+off; off=al256(off+bytes); return r; };
  float* dis    =(float*)alloc((size_t)NN*4);
  int*   cnt    =(int*)  alloc((size_t)NN*4);
  int*   offs   =(int*)  alloc((size_t)(NN+1)*4);
  int*   bsum   =(int*)  alloc((size_t)NB*4);
  int*   bpre   =(int*)  alloc((size_t)NB*4);
  int*   pos    =(int*)  alloc((size_t)NE*4);
  int2*  csr    =(int2*) alloc((size_t)NE*8);
  float* Wp     =(float*)alloc((size_t)3*48*48*4);
  float* Wgh    =(float*)alloc((size_t)6*48*24*4);
  unsigned* A   =(unsigned*)alloc((size_t)NN*576 + 1024);   // bf16 [n][f][t6], 576B/row
  float* h1     =(float*)alloc((size_t)NN*TT*HID*4);
  float* h2     =(float*)alloc((size_t)NN*TT*HID*4);
  // gi overlays dead A+h1 (86.4 MB <= 97.9 MB): written after k_agg layer-1 consumed both
  ushortT* gi   =(ushortT*)A;

  const int GN=(NN+255)/256, GE=(NE+255)/256;
  const int GMM=(NN+63)/64;              // 64 nodes/block, 4 waves (feature slices)
  const int GAGG=(NN*64+255)/256;        // 1 wave/node
  const int GGRU=(NN+63)/64;             // 64 nodes/block, 6 waves

  k_setup  <<<GN,256,0,stream>>>(cnt,Wih,Whh,Wp,Wgh);
  k_cnt    <<<GE,256,0,stream>>>(ei,cnt,pos);
  k_partA  <<<NB,256,0,stream>>>(cnt,bsum);
  k_midB   <<<1,256,0,stream>>>(bsum,bpre,offs);
  k_offsC  <<<NB,256,0,stream>>>(cnt,bpre,offs);
  k_scatter<<<GE,256,0,stream>>>(ei,ew,offs,pos,csr);
  k_deg    <<<GN,256,0,stream>>>(csr,offs,dis);
  k_normE  <<<GE,256,0,stream>>>(csr,dis);

  // layer 0
  k_mm0<<<GMM,256,0,stream>>>(x_seq, W0, A);
  k_agg<<<GAGG,256,0,stream>>>(A,b0,g0,be0,nullptr,h1,offs,csr,dis);
  // layer 1 (residual = h1)
  k_mm1<<<GMM,256,0,stream>>>(h1, W1, A);
  k_agg<<<GAGG,256,0,stream>>>(A,b1,g1,be1,h1,h2,offs,csr,dis);
  // gi = h2 @ Wih^T + bih (batched over all t), then recurrent-only GRU + classifier
  k_mmG<<<dim3(3,6,NB),256,0,stream>>>(h2, Wp, bih, gi);
  k_gruF<<<GGRU,384,0,stream>>>(gi, Wgh, bhh, Wc1,bc1,Wc2,bc2, outp);
}